// Round 18
// baseline (5484.362 us; speedup 1.0000x reference)
//
#include <hip/hip_runtime.h>
#include <hip/hip_bf16.h>

// Problem constants
constexpr int NB   = 32;    // batch
constexpr int NT   = 512;   // tokens
constexpr int ND   = 768;   // bert dim
constexpr int NW   = 255;   // words
constexpr int NH   = 768;   // lstm hidden
constexpr int NCLS = 9;     // NER classes
constexpr int NMTOT = NB * NW;          // 8160 rows
constexpr int NG4  = 4 * NH;            // 3072 gate dim
constexpr int PARSZ = NH * NB;          // 24576 floats per h parity buffer
constexpr int KR   = NH / 4;            // 192 k per k-quarter
constexpr int LROW = 772;               // padded LDS row stride (f32); 772=4*193,
                                        // 193 odd -> lbq stride sweeps all 8 bank groups

__device__ __forceinline__ float sigmoidf_(float x) {
    return 1.0f / (1.0f + expf(-x));
}

// ---------------------------------------------------------------------------
// Kernel 1 (VERBATIM, proven): first-subword index per (b, w).
// ---------------------------------------------------------------------------
__global__ void pool_idx_kernel(const int* __restrict__ word_ids,
                                int* __restrict__ rowbase) {
    int bb = blockIdx.x;
    int w = threadIdx.x;
    if (w >= NW) return;
    const int* row = word_ids + bb * NT;
    int ft = 0;
    for (int t = 0; t < NT; ++t) {
        if (row[t] == w) { ft = t; break; }
    }
    rowbase[bb * NW + w] = (bb * NT + ft) * ND;
}

// ---------------------------------------------------------------------------
// Kernel 2 (VERBATIM, proven): xg[dir] = pooled @ W_ih[dir]^T + b[dir] (f32)
// Row-major output xg[m][4H], m = b*NW + w.
// ---------------------------------------------------------------------------
__global__ __launch_bounds__(256) void gemm_xg_kernel(
    const float* __restrict__ bert, const int* __restrict__ rowbase,
    const float* __restrict__ Wf, const float* __restrict__ biasf,
    const float* __restrict__ Wb, const float* __restrict__ biasb,
    float* __restrict__ xgf, float* __restrict__ xgb) {
    const int dir = blockIdx.z;
    const float* Wt = dir ? Wb : Wf;
    const float* bias = dir ? biasb : biasf;
    float* xg = dir ? xgb : xgf;
    const int m0 = blockIdx.y * 128;
    const int n0 = blockIdx.x * 128;

    __shared__ float As[8][128];
    __shared__ float Bs[8][128];

    const int t = threadIdx.x;
    const int lrow = t >> 1;        // 0..127
    const int lk = (t & 1) * 4;     // 0 or 4

    int am = m0 + lrow;
    const float* aptr = bert + (am < NMTOT ? rowbase[am] : rowbase[NMTOT - 1]) + lk;
    const float* bptr = Wt + (size_t)(n0 + lrow) * ND + lk;

    const int tm = (t & 15) * 8;
    const int tn = (t >> 4) * 8;

    float acc[8][8] = {};

    for (int k0 = 0; k0 < ND; k0 += 8) {
        float4 av = *(const float4*)(aptr + k0);
        float4 bv = *(const float4*)(bptr + k0);
        __syncthreads();
        As[lk + 0][lrow] = av.x; As[lk + 1][lrow] = av.y;
        As[lk + 2][lrow] = av.z; As[lk + 3][lrow] = av.w;
        Bs[lk + 0][lrow] = bv.x; Bs[lk + 1][lrow] = bv.y;
        Bs[lk + 2][lrow] = bv.z; Bs[lk + 3][lrow] = bv.w;
        __syncthreads();
#pragma unroll
        for (int kk = 0; kk < 8; ++kk) {
            float ar[8], br[8];
#pragma unroll
            for (int i = 0; i < 8; ++i) ar[i] = As[kk][tm + i];
#pragma unroll
            for (int j = 0; j < 8; ++j) br[j] = Bs[kk][tn + j];
#pragma unroll
            for (int i = 0; i < 8; ++i)
#pragma unroll
                for (int j = 0; j < 8; ++j)
                    acc[i][j] = fmaf(ar[i], br[j], acc[i][j]);
        }
    }

#pragma unroll
    for (int i = 0; i < 8; ++i) {
        int m = m0 + tm + i;
        if (m >= NMTOT) continue;
        float* orow = xg + (size_t)m * NG4 + n0 + tn;
#pragma unroll
        for (int j = 0; j < 8; ++j) orow[j] = acc[i][j] + bias[n0 + tn + j];
    }
}

// ---------------------------------------------------------------------------
// Kernel 3: ONE LSTM time step (sequential launches, proven frame).
// R15 text + ONE change: batch pairing (lbq, lbq+8) instead of (2lbq, 2lbq+1)
// so the h dot-reads are LDS bank-conflict-free.
//   Old: lbq lane stride = 2*LROW = 1544 words ≡ 8 mod 32 -> lbq lanes alias
//        pairwise onto 4 bank-groups; + 4 ks lanes (stride 192 ≡ 0 mod 32)
//        -> 8 lanes per hot group, half the banks idle (~2x b128 cost).
//   New: lbq lane stride = LROW = 772 ≡ 4 mod 32 -> lbq 0..7 sweep all 8
//        bank-groups exactly once; 4 ks lanes per group at 4 words/bank =
//        perfectly even ds_read_b128.
// 256 blocks x 384 threads, 49408 B dynamic LDS.
// XCD remap (R15, proven): xcd = blk&7, ii = blk>>3; bh = ii&1,
// (dir,cg) = ((ii>>1)<<3)|xcd -> both bh halves of one weight slice on the
// same XCD; per-XCD weight footprint 2.36 MB < 4 MB L2.
// ---------------------------------------------------------------------------
__global__ __launch_bounds__(384) void lstm_step_kernel(
    const int s,
    const float* __restrict__ xgf, const float* __restrict__ xgb,
    const float* __restrict__ Whf, const float* __restrict__ Whb,
    float* __restrict__ hf_out, float* __restrict__ hb_out,
    float* __restrict__ hbuf /* [2 dir][2 par][PARSZ] */,
    float* __restrict__ cst  /* [2 dir][PARSZ] */) {
    extern __shared__ float hl[];     // [16][LROW]

    const int blk = blockIdx.x;       // 0..255
    // XCD-aware remap (bijective: (xcd, ii) <-> (dir, cg, bh)).
    const int xcd = blk & 7;
    const int ii  = blk >> 3;         // 0..31
    const int bh  = ii & 1;           // batch half
    const int idx = ((ii >> 1) << 3) | xcd;   // 0..127 distinct (dir,cg)
    const int dir = idx >> 6;
    const int cg  = idx & 63;

    const int t = threadIdx.x;        // 0..383
    const int ci = t >> 5;            // 0..11 local col
    const int ks = (t >> 3) & 3;      // 0..3 k quarter
    const int lbq = t & 7;            // 0..7 batch pair id
    const int col = cg * 12 + ci;
    const int b0l = lbq;              // local batch of acc .x  (0..7)
    const int b1l = lbq + 8;          // local batch of acc .y  (8..15)
    const int bbase = bh * 16;        // global batch base
    const int ksk = ks * KR;          // k-quarter base

    const float* Wh = dir ? Whb : Whf;
    const float* xg = dir ? xgb : xgf;
    float* hout = dir ? hb_out : hf_out;
    float* hbase = hbuf + (size_t)dir * 2 * PARSZ;
    float* cbase = cst + (size_t)dir * PARSZ;

    const int p = dir ? (NW - 1 - s) : s;

    // ---- Stage h[bbase..bbase+15][0..767] -> LDS [16][LROW]
    {
        const float* hcur = hbase + (s & 1) * PARSZ;
        for (int idx2 = t; idx2 < 16 * 192; idx2 += 384) {
            const int b = idx2 / 192;
            const int kq = idx2 - b * 192;        // float4 index in k
            float4 v = *(const float4*)(hcur + (size_t)(bbase + b) * NH + kq * 4);
            *(float4*)(hl + (size_t)b * LROW + kq * 4) = v;
        }
    }
    __syncthreads();

    // Per-thread weight row pointers (gate g row = Wh[g*NH+col][ksk..+192)).
    const float4* W0 = (const float4*)(Wh + ((size_t)(0 * NH + col)) * NH + ksk);
    const float4* W1 = (const float4*)(Wh + ((size_t)(1 * NH + col)) * NH + ksk);
    const float4* W2 = (const float4*)(Wh + ((size_t)(2 * NH + col)) * NH + ksk);
    const float4* W3 = (const float4*)(Wh + ((size_t)(3 * NH + col)) * NH + ksk);

    // LDS h rows for this thread's 2 batches (rows lbq and lbq+8), k-quarter.
    const float4* h0 = (const float4*)(hl + (size_t)b0l * LROW + ksk);
    const float4* h1 = (const float4*)(hl + (size_t)b1l * LROW + ksk);

    float2 accI = {0,0}, accF = {0,0}, accG = {0,0}, accO = {0,0};
#pragma unroll 4
    for (int u = 0; u < KR / 4; ++u) {
        float4 w0 = W0[u], w1 = W1[u], w2 = W2[u], w3 = W3[u];
        float4 a = h0[u], b = h1[u];
        // gate i
        accI.x = fmaf(a.x, w0.x, accI.x); accI.x = fmaf(a.y, w0.y, accI.x);
        accI.x = fmaf(a.z, w0.z, accI.x); accI.x = fmaf(a.w, w0.w, accI.x);
        accI.y = fmaf(b.x, w0.x, accI.y); accI.y = fmaf(b.y, w0.y, accI.y);
        accI.y = fmaf(b.z, w0.z, accI.y); accI.y = fmaf(b.w, w0.w, accI.y);
        // gate f
        accF.x = fmaf(a.x, w1.x, accF.x); accF.x = fmaf(a.y, w1.y, accF.x);
        accF.x = fmaf(a.z, w1.z, accF.x); accF.x = fmaf(a.w, w1.w, accF.x);
        accF.y = fmaf(b.x, w1.x, accF.y); accF.y = fmaf(b.y, w1.y, accF.y);
        accF.y = fmaf(b.z, w1.z, accF.y); accF.y = fmaf(b.w, w1.w, accF.y);
        // gate g
        accG.x = fmaf(a.x, w2.x, accG.x); accG.x = fmaf(a.y, w2.y, accG.x);
        accG.x = fmaf(a.z, w2.z, accG.x); accG.x = fmaf(a.w, w2.w, accG.x);
        accG.y = fmaf(b.x, w2.x, accG.y); accG.y = fmaf(b.y, w2.y, accG.y);
        accG.y = fmaf(b.z, w2.z, accG.y); accG.y = fmaf(b.w, w2.w, accG.y);
        // gate o
        accO.x = fmaf(a.x, w3.x, accO.x); accO.x = fmaf(a.y, w3.y, accO.x);
        accO.x = fmaf(a.z, w3.z, accO.x); accO.x = fmaf(a.w, w3.w, accO.x);
        accO.y = fmaf(b.x, w3.x, accO.y); accO.y = fmaf(b.y, w3.y, accO.y);
        accO.y = fmaf(b.z, w3.z, accO.y); accO.y = fmaf(b.w, w3.w, accO.y);
    }

    // Combine the 4 k-quarters: lane bits 3..4 encode ks (same as R11/R14/R15).
#pragma unroll
    for (int off = 8; off <= 16; off <<= 1) {
        accI.x += __shfl_xor(accI.x, off); accI.y += __shfl_xor(accI.y, off);
        accF.x += __shfl_xor(accF.x, off); accF.y += __shfl_xor(accF.y, off);
        accG.x += __shfl_xor(accG.x, off); accG.y += __shfl_xor(accG.y, off);
        accO.x += __shfl_xor(accO.x, off); accO.y += __shfl_xor(accO.y, off);
    }

    if (ks == 0) {
        const int b0g = bbase + b0l;          // global batch of .x
        const int b1g = bbase + b1l;          // global batch of .y
        // xg gathers: xg[m][4H], m = b*NW + p (R11-proven addressing).
        const size_t a0 = ((size_t)b0g * NW + p) * NG4 + col;
        const size_t a1 = ((size_t)b1g * NW + p) * NG4 + col;
        float2 xgi, xgF, xgG, xgO;
        xgi.x = xg[a0];          xgi.y = xg[a1];
        xgF.x = xg[a0 + NH];     xgF.y = xg[a1 + NH];
        xgG.x = xg[a0 + 2*NH];   xgG.y = xg[a1 + 2*NH];
        xgO.x = xg[a0 + 3*NH];   xgO.y = xg[a1 + 3*NH];

        float2 c2;
        c2.x = cbase[(size_t)b0g * NH + col];
        c2.y = cbase[(size_t)b1g * NH + col];

        float2 h2;
#define ACT1(JX) { \
        float iG = sigmoidf_(accI.JX + xgi.JX); \
        float fG = sigmoidf_(accF.JX + xgF.JX); \
        float gG = tanhf(accG.JX + xgG.JX); \
        float oG = sigmoidf_(accO.JX + xgO.JX); \
        c2.JX = fG * c2.JX + iG * gG; \
        h2.JX = oG * tanhf(c2.JX); }
        ACT1(x) ACT1(y)
#undef ACT1

        cbase[(size_t)b0g * NH + col] = c2.x;
        cbase[(size_t)b1g * NH + col] = c2.y;

        float* hnxt = hbase + ((s + 1) & 1) * PARSZ;
        hnxt[(size_t)b0g * NH + col] = h2.x;
        hnxt[(size_t)b1g * NH + col] = h2.y;

        hout[((size_t)b0g * NW + p) * NH + col] = h2.x;
        hout[((size_t)b1g * NW + p) * NH + col] = h2.y;
    }
}

// ---------------------------------------------------------------------------
// Kernel 4 (VERBATIM, proven): head — logits, softmax, argmax.
// ---------------------------------------------------------------------------
__global__ __launch_bounds__(64) void head_kernel(
    const float* __restrict__ hf, const float* __restrict__ hb,
    const float* __restrict__ Wl, const float* __restrict__ bl,
    float* __restrict__ out) {
    const int m = blockIdx.x;      // 0..8159
    const int lane = threadIdx.x;  // 0..63
    float acc[NCLS];
#pragma unroll
    for (int cI = 0; cI < NCLS; ++cI) acc[cI] = 0.0f;

    const float* hfr = hf + (size_t)m * NH;
    const float* hbr = hb + (size_t)m * NH;
    for (int j = lane; j < NH; j += 64) {
        float v1 = hfr[j];
        float v2 = hbr[j];
#pragma unroll
        for (int cI = 0; cI < NCLS; ++cI) {
            acc[cI] = fmaf(v1, Wl[cI * 2 * NH + j], acc[cI]);
            acc[cI] = fmaf(v2, Wl[cI * 2 * NH + NH + j], acc[cI]);
        }
    }
#pragma unroll
    for (int cI = 0; cI < NCLS; ++cI)
        for (int off = 32; off > 0; off >>= 1)
            acc[cI] += __shfl_down(acc[cI], off);

    if (lane == 0) {
        float logit[NCLS];
        float mx = -1e30f;
#pragma unroll
        for (int cI = 0; cI < NCLS; ++cI) {
            logit[cI] = acc[cI] + bl[cI];
            mx = fmaxf(mx, logit[cI]);
        }
        float e[NCLS];
        float sum = 0.0f;
#pragma unroll
        for (int cI = 0; cI < NCLS; ++cI) { e[cI] = expf(logit[cI] - mx); sum += e[cI]; }
        float inv = 1.0f / sum;
        int best = 0;
        float bestv = -1.0f;
#pragma unroll
        for (int cI = 0; cI < NCLS; ++cI) {
            float p = e[cI] * inv;
            out[(size_t)m * NCLS + cI] = p;
            if (p > bestv) { bestv = p; best = cI; }  // first-occurrence argmax
        }
        out[(size_t)NMTOT * NCLS + m] = (float)best;
    }
}

// ---------------------------------------------------------------------------
extern "C" void kernel_launch(void* const* d_in, const int* in_sizes, int n_in,
                              void* d_out, int out_size, void* d_ws, size_t ws_size,
                              hipStream_t stream) {
    const float* bert     = (const float*)d_in[0];
    const int*   word_ids = (const int*)d_in[1];
    const float* W_ih_f   = (const float*)d_in[2];
    const float* W_hh_f   = (const float*)d_in[3];
    const float* b_f      = (const float*)d_in[4];
    const float* W_ih_b   = (const float*)d_in[5];
    const float* W_hh_b   = (const float*)d_in[6];
    const float* b_b      = (const float*)d_in[7];
    const float* W_lin    = (const float*)d_in[8];
    const float* b_lin    = (const float*)d_in[9];
    float* out = (float*)d_out;   // f32: prob [8160*9] then path [8160]

    char* ws = (char*)d_ws;
    size_t off = 0;
    auto alloc = [&](size_t bytes) -> void* {
        void* p = ws + off;
        off += (bytes + 255) & ~(size_t)255;
        return p;
    };
    int*   rowbase = (int*)alloc((size_t)NMTOT * sizeof(int));
    float* xgf = (float*)alloc((size_t)NMTOT * NG4 * sizeof(float));   // 100 MB
    float* xgb = (float*)alloc((size_t)NMTOT * NG4 * sizeof(float));   // 100 MB
    float* hf  = (float*)alloc((size_t)NMTOT * NH * sizeof(float));    // 25 MB
    float* hb  = (float*)alloc((size_t)NMTOT * NH * sizeof(float));    // 25 MB
    float* hbuf = (float*)alloc((size_t)4 * PARSZ * sizeof(float));    // 384 KB
    float* cst  = (float*)alloc((size_t)2 * PARSZ * sizeof(float));    // 192 KB

    pool_idx_kernel<<<NB, 256, 0, stream>>>(word_ids, rowbase);

    dim3 ggrid(NG4 / 128, (NMTOT + 127) / 128, 2);
    gemm_xg_kernel<<<ggrid, 256, 0, stream>>>(bert, rowbase, W_ih_f, b_f,
                                              W_ih_b, b_b, xgf, xgb);

    // Zero recurrence state (ws is poisoned before every call).
    hipMemsetAsync(hbuf, 0, (size_t)4 * PARSZ * sizeof(float), stream);
    hipMemsetAsync(cst,  0, (size_t)2 * PARSZ * sizeof(float), stream);

    // 255 sequential per-step launches: kernel boundary = grid-wide barrier.
    const size_t lds_bytes = (size_t)16 * LROW * sizeof(float);  // 49408 B
    for (int s = 0; s < NW; ++s) {
        lstm_step_kernel<<<dim3(256), dim3(384), lds_bytes, stream>>>(
            s, xgf, xgb, W_hh_f, W_hh_b, hf, hb, hbuf, cst);
    }

    head_kernel<<<NMTOT, 64, 0, stream>>>(hf, hb, W_lin, b_lin, out);
}

// Round 19
// 5372.010 us; speedup vs baseline: 1.0209x; 1.0209x over previous
//
#include <hip/hip_runtime.h>
#include <hip/hip_bf16.h>

// Problem constants
constexpr int NB   = 32;    // batch
constexpr int NT   = 512;   // tokens
constexpr int ND   = 768;   // bert dim
constexpr int NW   = 255;   // words
constexpr int NH   = 768;   // lstm hidden
constexpr int NCLS = 9;     // NER classes
constexpr int NMTOT = NB * NW;          // 8160 rows
constexpr int NG4  = 4 * NH;            // 3072 gate dim
constexpr int PARSZ = NH * NB;          // 24576 floats per h parity buffer
constexpr int KR   = NH / 4;            // 192 k per k-quarter
constexpr int LROW = 772;               // padded LDS row stride (f32)

__device__ __forceinline__ float sigmoidf_(float x) {
    return 1.0f / (1.0f + expf(-x));
}

// ---------------------------------------------------------------------------
// Kernel 1 (VERBATIM, proven): first-subword index per (b, w).
// ---------------------------------------------------------------------------
__global__ void pool_idx_kernel(const int* __restrict__ word_ids,
                                int* __restrict__ rowbase) {
    int bb = blockIdx.x;
    int w = threadIdx.x;
    if (w >= NW) return;
    const int* row = word_ids + bb * NT;
    int ft = 0;
    for (int t = 0; t < NT; ++t) {
        if (row[t] == w) { ft = t; break; }
    }
    rowbase[bb * NW + w] = (bb * NT + ft) * ND;
}

// ---------------------------------------------------------------------------
// Kernel 2: xg GEMM — R18 text + ONE change: software-prefetch double-buffer.
// The old loop exposed ~450 cy of global-load latency EVERY k-iteration
// (load -> sync -> LDS-write needs the load). Now iteration k0 computes while
// k0+8's av/bv are in flight; the waitcnt lands at the next LDS write, after
// ~1024 cy of FMA. Tile/epilogue/layout byte-identical.
// ---------------------------------------------------------------------------
__global__ __launch_bounds__(256) void gemm_xg_kernel(
    const float* __restrict__ bert, const int* __restrict__ rowbase,
    const float* __restrict__ Wf, const float* __restrict__ biasf,
    const float* __restrict__ Wb, const float* __restrict__ biasb,
    float* __restrict__ xgf, float* __restrict__ xgb) {
    const int dir = blockIdx.z;
    const float* Wt = dir ? Wb : Wf;
    const float* bias = dir ? biasb : biasf;
    float* xg = dir ? xgb : xgf;
    const int m0 = blockIdx.y * 128;
    const int n0 = blockIdx.x * 128;

    __shared__ float As[8][128];
    __shared__ float Bs[8][128];

    const int t = threadIdx.x;
    const int lrow = t >> 1;        // 0..127
    const int lk = (t & 1) * 4;     // 0 or 4

    int am = m0 + lrow;
    const float* aptr = bert + (am < NMTOT ? rowbase[am] : rowbase[NMTOT - 1]) + lk;
    const float* bptr = Wt + (size_t)(n0 + lrow) * ND + lk;

    const int tm = (t & 15) * 8;
    const int tn = (t >> 4) * 8;

    float acc[8][8] = {};

    // Prefetch k0 = 0.
    float4 av = *(const float4*)(aptr);
    float4 bv = *(const float4*)(bptr);

    for (int k0 = 0; k0 < ND; k0 += 8) {
        __syncthreads();
        As[lk + 0][lrow] = av.x; As[lk + 1][lrow] = av.y;
        As[lk + 2][lrow] = av.z; As[lk + 3][lrow] = av.w;
        Bs[lk + 0][lrow] = bv.x; Bs[lk + 1][lrow] = bv.y;
        Bs[lk + 2][lrow] = bv.z; Bs[lk + 3][lrow] = bv.w;
        __syncthreads();
        // Issue next tile's loads NOW; consumed at the next LDS write,
        // after the FMA block below (hides global latency).
        float4 av2 = av, bv2 = bv;
        if (k0 + 8 < ND) {
            av2 = *(const float4*)(aptr + k0 + 8);
            bv2 = *(const float4*)(bptr + k0 + 8);
        }
#pragma unroll
        for (int kk = 0; kk < 8; ++kk) {
            float ar[8], br[8];
#pragma unroll
            for (int i = 0; i < 8; ++i) ar[i] = As[kk][tm + i];
#pragma unroll
            for (int j = 0; j < 8; ++j) br[j] = Bs[kk][tn + j];
#pragma unroll
            for (int i = 0; i < 8; ++i)
#pragma unroll
                for (int j = 0; j < 8; ++j)
                    acc[i][j] = fmaf(ar[i], br[j], acc[i][j]);
        }
        av = av2; bv = bv2;
    }

#pragma unroll
    for (int i = 0; i < 8; ++i) {
        int m = m0 + tm + i;
        if (m >= NMTOT) continue;
        float* orow = xg + (size_t)m * NG4 + n0 + tn;
#pragma unroll
        for (int j = 0; j < 8; ++j) orow[j] = acc[i][j] + bias[n0 + tn + j];
    }
}

// ---------------------------------------------------------------------------
// Kernel 3 (VERBATIM from R18, measured 5.48 ms anchor): ONE LSTM time step.
// 256 blocks x 384 threads, 49408 B dynamic LDS, sequential launches.
// XCD remap (R15): both bh halves of one weight slice on the same XCD.
// ---------------------------------------------------------------------------
__global__ __launch_bounds__(384) void lstm_step_kernel(
    const int s,
    const float* __restrict__ xgf, const float* __restrict__ xgb,
    const float* __restrict__ Whf, const float* __restrict__ Whb,
    float* __restrict__ hf_out, float* __restrict__ hb_out,
    float* __restrict__ hbuf /* [2 dir][2 par][PARSZ] */,
    float* __restrict__ cst  /* [2 dir][PARSZ] */) {
    extern __shared__ float hl[];     // [16][LROW]

    const int blk = blockIdx.x;       // 0..255
    // XCD-aware remap (bijective: (xcd, ii) <-> (dir, cg, bh)).
    const int xcd = blk & 7;
    const int ii  = blk >> 3;         // 0..31
    const int bh  = ii & 1;           // batch half
    const int idx = ((ii >> 1) << 3) | xcd;   // 0..127 distinct (dir,cg)
    const int dir = idx >> 6;
    const int cg  = idx & 63;

    const int t = threadIdx.x;        // 0..383
    const int ci = t >> 5;            // 0..11 local col
    const int ks = (t >> 3) & 3;      // 0..3 k quarter
    const int lbq = t & 7;            // 0..7 batch pair id
    const int col = cg * 12 + ci;
    const int b0l = lbq;              // local batch of acc .x  (0..7)
    const int b1l = lbq + 8;          // local batch of acc .y  (8..15)
    const int bbase = bh * 16;        // global batch base
    const int ksk = ks * KR;          // k-quarter base

    const float* Wh = dir ? Whb : Whf;
    const float* xg = dir ? xgb : xgf;
    float* hout = dir ? hb_out : hf_out;
    float* hbase = hbuf + (size_t)dir * 2 * PARSZ;
    float* cbase = cst + (size_t)dir * PARSZ;

    const int p = dir ? (NW - 1 - s) : s;

    // ---- Stage h[bbase..bbase+15][0..767] -> LDS [16][LROW]
    {
        const float* hcur = hbase + (s & 1) * PARSZ;
        for (int idx2 = t; idx2 < 16 * 192; idx2 += 384) {
            const int b = idx2 / 192;
            const int kq = idx2 - b * 192;        // float4 index in k
            float4 v = *(const float4*)(hcur + (size_t)(bbase + b) * NH + kq * 4);
            *(float4*)(hl + (size_t)b * LROW + kq * 4) = v;
        }
    }
    __syncthreads();

    // Per-thread weight row pointers (gate g row = Wh[g*NH+col][ksk..+192)).
    const float4* W0 = (const float4*)(Wh + ((size_t)(0 * NH + col)) * NH + ksk);
    const float4* W1 = (const float4*)(Wh + ((size_t)(1 * NH + col)) * NH + ksk);
    const float4* W2 = (const float4*)(Wh + ((size_t)(2 * NH + col)) * NH + ksk);
    const float4* W3 = (const float4*)(Wh + ((size_t)(3 * NH + col)) * NH + ksk);

    // LDS h rows for this thread's 2 batches (rows lbq and lbq+8), k-quarter.
    const float4* h0 = (const float4*)(hl + (size_t)b0l * LROW + ksk);
    const float4* h1 = (const float4*)(hl + (size_t)b1l * LROW + ksk);

    float2 accI = {0,0}, accF = {0,0}, accG = {0,0}, accO = {0,0};
#pragma unroll 4
    for (int u = 0; u < KR / 4; ++u) {
        float4 w0 = W0[u], w1 = W1[u], w2 = W2[u], w3 = W3[u];
        float4 a = h0[u], b = h1[u];
        // gate i
        accI.x = fmaf(a.x, w0.x, accI.x); accI.x = fmaf(a.y, w0.y, accI.x);
        accI.x = fmaf(a.z, w0.z, accI.x); accI.x = fmaf(a.w, w0.w, accI.x);
        accI.y = fmaf(b.x, w0.x, accI.y); accI.y = fmaf(b.y, w0.y, accI.y);
        accI.y = fmaf(b.z, w0.z, accI.y); accI.y = fmaf(b.w, w0.w, accI.y);
        // gate f
        accF.x = fmaf(a.x, w1.x, accF.x); accF.x = fmaf(a.y, w1.y, accF.x);
        accF.x = fmaf(a.z, w1.z, accF.x); accF.x = fmaf(a.w, w1.w, accF.x);
        accF.y = fmaf(b.x, w1.x, accF.y); accF.y = fmaf(b.y, w1.y, accF.y);
        accF.y = fmaf(b.z, w1.z, accF.y); accF.y = fmaf(b.w, w1.w, accF.y);
        // gate g
        accG.x = fmaf(a.x, w2.x, accG.x); accG.x = fmaf(a.y, w2.y, accG.x);
        accG.x = fmaf(a.z, w2.z, accG.x); accG.x = fmaf(a.w, w2.w, accG.x);
        accG.y = fmaf(b.x, w2.x, accG.y); accG.y = fmaf(b.y, w2.y, accG.y);
        accG.y = fmaf(b.z, w2.z, accG.y); accG.y = fmaf(b.w, w2.w, accG.y);
        // gate o
        accO.x = fmaf(a.x, w3.x, accO.x); accO.x = fmaf(a.y, w3.y, accO.x);
        accO.x = fmaf(a.z, w3.z, accO.x); accO.x = fmaf(a.w, w3.w, accO.x);
        accO.y = fmaf(b.x, w3.x, accO.y); accO.y = fmaf(b.y, w3.y, accO.y);
        accO.y = fmaf(b.z, w3.z, accO.y); accO.y = fmaf(b.w, w3.w, accO.y);
    }

    // Combine the 4 k-quarters: lane bits 3..4 encode ks.
#pragma unroll
    for (int off = 8; off <= 16; off <<= 1) {
        accI.x += __shfl_xor(accI.x, off); accI.y += __shfl_xor(accI.y, off);
        accF.x += __shfl_xor(accF.x, off); accF.y += __shfl_xor(accF.y, off);
        accG.x += __shfl_xor(accG.x, off); accG.y += __shfl_xor(accG.y, off);
        accO.x += __shfl_xor(accO.x, off); accO.y += __shfl_xor(accO.y, off);
    }

    if (ks == 0) {
        const int b0g = bbase + b0l;          // global batch of .x
        const int b1g = bbase + b1l;          // global batch of .y
        // xg gathers: xg[m][4H], m = b*NW + p (R11-proven addressing).
        const size_t a0 = ((size_t)b0g * NW + p) * NG4 + col;
        const size_t a1 = ((size_t)b1g * NW + p) * NG4 + col;
        float2 xgi, xgF, xgG, xgO;
        xgi.x = xg[a0];          xgi.y = xg[a1];
        xgF.x = xg[a0 + NH];     xgF.y = xg[a1 + NH];
        xgG.x = xg[a0 + 2*NH];   xgG.y = xg[a1 + 2*NH];
        xgO.x = xg[a0 + 3*NH];   xgO.y = xg[a1 + 3*NH];

        float2 c2;
        c2.x = cbase[(size_t)b0g * NH + col];
        c2.y = cbase[(size_t)b1g * NH + col];

        float2 h2;
#define ACT1(JX) { \
        float iG = sigmoidf_(accI.JX + xgi.JX); \
        float fG = sigmoidf_(accF.JX + xgF.JX); \
        float gG = tanhf(accG.JX + xgG.JX); \
        float oG = sigmoidf_(accO.JX + xgO.JX); \
        c2.JX = fG * c2.JX + iG * gG; \
        h2.JX = oG * tanhf(c2.JX); }
        ACT1(x) ACT1(y)
#undef ACT1

        cbase[(size_t)b0g * NH + col] = c2.x;
        cbase[(size_t)b1g * NH + col] = c2.y;

        float* hnxt = hbase + ((s + 1) & 1) * PARSZ;
        hnxt[(size_t)b0g * NH + col] = h2.x;
        hnxt[(size_t)b1g * NH + col] = h2.y;

        hout[((size_t)b0g * NW + p) * NH + col] = h2.x;
        hout[((size_t)b1g * NW + p) * NH + col] = h2.y;
    }
}

// ---------------------------------------------------------------------------
// Kernel 4 (VERBATIM, proven): head — logits, softmax, argmax.
// ---------------------------------------------------------------------------
__global__ __launch_bounds__(64) void head_kernel(
    const float* __restrict__ hf, const float* __restrict__ hb,
    const float* __restrict__ Wl, const float* __restrict__ bl,
    float* __restrict__ out) {
    const int m = blockIdx.x;      // 0..8159
    const int lane = threadIdx.x;  // 0..63
    float acc[NCLS];
#pragma unroll
    for (int cI = 0; cI < NCLS; ++cI) acc[cI] = 0.0f;

    const float* hfr = hf + (size_t)m * NH;
    const float* hbr = hb + (size_t)m * NH;
    for (int j = lane; j < NH; j += 64) {
        float v1 = hfr[j];
        float v2 = hbr[j];
#pragma unroll
        for (int cI = 0; cI < NCLS; ++cI) {
            acc[cI] = fmaf(v1, Wl[cI * 2 * NH + j], acc[cI]);
            acc[cI] = fmaf(v2, Wl[cI * 2 * NH + NH + j], acc[cI]);
        }
    }
#pragma unroll
    for (int cI = 0; cI < NCLS; ++cI)
        for (int off = 32; off > 0; off >>= 1)
            acc[cI] += __shfl_down(acc[cI], off);

    if (lane == 0) {
        float logit[NCLS];
        float mx = -1e30f;
#pragma unroll
        for (int cI = 0; cI < NCLS; ++cI) {
            logit[cI] = acc[cI] + bl[cI];
            mx = fmaxf(mx, logit[cI]);
        }
        float e[NCLS];
        float sum = 0.0f;
#pragma unroll
        for (int cI = 0; cI < NCLS; ++cI) { e[cI] = expf(logit[cI] - mx); sum += e[cI]; }
        float inv = 1.0f / sum;
        int best = 0;
        float bestv = -1.0f;
#pragma unroll
        for (int cI = 0; cI < NCLS; ++cI) {
            float p = e[cI] * inv;
            out[(size_t)m * NCLS + cI] = p;
            if (p > bestv) { bestv = p; best = cI; }  // first-occurrence argmax
        }
        out[(size_t)NMTOT * NCLS + m] = (float)best;
    }
}

// ---------------------------------------------------------------------------
extern "C" void kernel_launch(void* const* d_in, const int* in_sizes, int n_in,
                              void* d_out, int out_size, void* d_ws, size_t ws_size,
                              hipStream_t stream) {
    const float* bert     = (const float*)d_in[0];
    const int*   word_ids = (const int*)d_in[1];
    const float* W_ih_f   = (const float*)d_in[2];
    const float* W_hh_f   = (const float*)d_in[3];
    const float* b_f      = (const float*)d_in[4];
    const float* W_ih_b   = (const float*)d_in[5];
    const float* W_hh_b   = (const float*)d_in[6];
    const float* b_b      = (const float*)d_in[7];
    const float* W_lin    = (const float*)d_in[8];
    const float* b_lin    = (const float*)d_in[9];
    float* out = (float*)d_out;   // f32: prob [8160*9] then path [8160]

    char* ws = (char*)d_ws;
    size_t off = 0;
    auto alloc = [&](size_t bytes) -> void* {
        void* p = ws + off;
        off += (bytes + 255) & ~(size_t)255;
        return p;
    };
    int*   rowbase = (int*)alloc((size_t)NMTOT * sizeof(int));
    float* xgf = (float*)alloc((size_t)NMTOT * NG4 * sizeof(float));   // 100 MB
    float* xgb = (float*)alloc((size_t)NMTOT * NG4 * sizeof(float));   // 100 MB
    float* hf  = (float*)alloc((size_t)NMTOT * NH * sizeof(float));    // 25 MB
    float* hb  = (float*)alloc((size_t)NMTOT * NH * sizeof(float));    // 25 MB
    float* hbuf = (float*)alloc((size_t)4 * PARSZ * sizeof(float));    // 384 KB
    float* cst  = (float*)alloc((size_t)2 * PARSZ * sizeof(float));    // 192 KB

    pool_idx_kernel<<<NB, 256, 0, stream>>>(word_ids, rowbase);

    dim3 ggrid(NG4 / 128, (NMTOT + 127) / 128, 2);
    gemm_xg_kernel<<<ggrid, 256, 0, stream>>>(bert, rowbase, W_ih_f, b_f,
                                              W_ih_b, b_b, xgf, xgb);

    // Zero recurrence state (ws is poisoned before every call).
    hipMemsetAsync(hbuf, 0, (size_t)4 * PARSZ * sizeof(float), stream);
    hipMemsetAsync(cst,  0, (size_t)2 * PARSZ * sizeof(float), stream);

    // 255 sequential per-step launches: kernel boundary = grid-wide barrier.
    const size_t lds_bytes = (size_t)16 * LROW * sizeof(float);  // 49408 B
    for (int s = 0; s < NW; ++s) {
        lstm_step_kernel<<<dim3(256), dim3(384), lds_bytes, stream>>>(
            s, xgf, xgb, W_hh_f, W_hh_b, hf, hb, hbuf, cst);
    }

    head_kernel<<<NMTOT, 64, 0, stream>>>(hf, hb, W_lin, b_lin, out);
}